// Round 14
// baseline (119.209 us; speedup 1.0000x reference)
//
#include <hip/hip_runtime.h>
#include <stdint.h>

typedef unsigned long long u64;
typedef unsigned int u32;
typedef int v4i  __attribute__((ext_vector_type(4)));
typedef int v16i __attribute__((ext_vector_type(16)));

#define NUM_TRAIN   50000
#define NUM_TEST    4096
#define CLASS_SIZE  5000
#define TRAIN_PAD   50176              // 1568 tiles of 32 rows
#define TOT_TILES   1568

// ws layout: train_i8 | test_i8 | te_sum | partial
#define SZ_TRAIN   ((size_t)TRAIN_PAD * 256)          // 12,845,056
#define SZ_TEST    ((size_t)NUM_TEST * 256)           //  1,048,576
#define SZ_TESUM   ((size_t)NUM_TEST * 4)             //     16,384
#define OFF_TEST   (SZ_TRAIN)
#define OFF_TESUM  (OFF_TEST + SZ_TEST)
#define OFF_PART   (OFF_TESUM + SZ_TESUM)             // 13,910,016
#define WS_NEED(NCH) (OFF_PART + (size_t)NUM_TEST * (NCH) * 3 * 4)

// ---------------------------------------------------------------------------
// Top-3 primitives (validated R2/R5/R6/R9/R10/R12/R13). key = (dist<<16)+idx
// encodes the reference (dist asc, then smaller index) tie-break exactly.
// ---------------------------------------------------------------------------
__device__ __forceinline__ void insert3(u32& k0, u32& k1, u32& k2, u32 key) {
    u32 m0 = min(k0, key);
    u32 m1 = min(k1, max(k0, key));
    u32 m2 = min(k2, max(k1, key));
    k0 = m0; k1 = m1; k2 = m2;
}
__device__ __forceinline__ void merge3(u32& a0, u32& a1, u32& a2,
                                       u32 b0, u32 b1, u32 b2) {
    u32 hi0 = max(a0, b0);
    u32 lo1 = min(a1, b1);
    u32 c0  = min(a0, b0);
    u32 c1  = min(hi0, lo1);
    u32 c2  = min(max(lo1, hi0), min(a2, b2));
    a0 = c0; a1 = c1; a2 = c2;
}
__device__ __forceinline__ int wave_sum(int s) {
    #pragma unroll
    for (int off = 1; off < 64; off <<= 1) s += __shfl_xor(s, off);
    return s;
}

// ---------------------------------------------------------------------------
// pack_train_bits: A byte = bit (0/1), 256 B/row. Pad rows (>=50000) zero.
// ---------------------------------------------------------------------------
__global__ __launch_bounds__(256) void pack_train_bits(const int* __restrict__ train,
                                                       char* __restrict__ dst) {
    int r    = (blockIdx.x * 256 + threadIdx.x) >> 6;
    int lane = threadIdx.x & 63;
    int4 v = make_int4(0, 0, 0, 0);
    if (r < NUM_TRAIN) v = *reinterpret_cast<const int4*>(train + (size_t)r * 256 + lane * 4);
    u32 w = (u32)(v.x & 1) | ((u32)(v.y & 1) << 8)
          | ((u32)(v.z & 1) << 16) | ((u32)(v.w & 1) << 24);
    *reinterpret_cast<u32*>(dst + (size_t)r * 256 + lane * 4) = w;
}

// pack_test_pm1: B byte = 1-2*bit (+1/-1); also writes te_sum[row].
__global__ __launch_bounds__(256) void pack_test_pm1(const int* __restrict__ test,
                                                     char* __restrict__ dst,
                                                     int* __restrict__ tesum) {
    int r    = (blockIdx.x * 256 + threadIdx.x) >> 6;
    int lane = threadIdx.x & 63;
    int4 v = *reinterpret_cast<const int4*>(test + (size_t)r * 256 + lane * 4);
    u32 w = (u32)((1 - 2 * v.x) & 0xFF) | ((u32)((1 - 2 * v.y) & 0xFF) << 8)
          | ((u32)((1 - 2 * v.z) & 0xFF) << 16) | ((u32)((1 - 2 * v.w) & 0xFF) << 24);
    *reinterpret_cast<u32*>(dst + (size_t)r * 256 + lane * 4) = w;
    int total = wave_sum(v.x + v.y + v.z + v.w);
    if (lane == 0) tesum[r] = total;
}

// ---------------------------------------------------------------------------
// mfma_knn (R14: L2-direct, ZERO LDS, ZERO barriers): block (cg = bid/NCH,
// c = bid%NCH); wave wid owns 128 test cols (4 B-frag sets in registers) and
// streams its chunk's A-fragments straight from global/L2 — no staging, no
// cross-wave coupling, waves slide freely past each other.
//   A-reuse: chunk c read by 8 blocks at blockIdx ≡ c (mod 8) -> same XCD ->
//   one L2 copy; per-XCD set ~2.6 MB < 4 MB L2. A traffic 411 MB ≈ 12 µs.
//   Per kk: 1 dwordx4 load feeds 4 independent MFMAs (latency hidden).
// acc = tr_sum - 2*inner; dist = acc + te_sum folded into the key base.
// Guarded epilogue nulls pad rows (idx >= 50000) on boundary tiles only.
// Fragment mapping / key arithmetic byte-identical to R10-R13 (validated).
// ---------------------------------------------------------------------------
template<int NCH>
__global__ __launch_bounds__(256, 2) void mfma_knn(const char* __restrict__ A,
                                                   const char* __restrict__ Bt,
                                                   const int* __restrict__ tesum,
                                                   u32* __restrict__ partial) {
    constexpr int TILES  = TOT_TILES / NCH;    // 14 (NCH=112) or 28 (NCH=56)
    constexpr int CHROWS = TRAIN_PAD / NCH;    // 448 or 896
    const int cg   = blockIdx.x / NCH;
    const int c    = blockIdx.x % NCH;
    const int wid  = threadIdx.x >> 6;
    const int lane = threadIdx.x & 63;
    const int a    = lane & 31;                // A-row within tile / B-col lane
    const int kh   = lane >> 5;                // K-half

    // Four B-fragment sets: this wave's 128 test cols, 8 K-steps, registers.
    const int colbase = cg * 512 + wid * 128 + a;
    v4i bf0[8], bf1[8], bf2[8], bf3[8];
    {
        const char* bp0 = Bt + (size_t)(colbase      ) * 256 + kh * 16;
        const char* bp1 = Bt + (size_t)(colbase + 32 ) * 256 + kh * 16;
        const char* bp2 = Bt + (size_t)(colbase + 64 ) * 256 + kh * 16;
        const char* bp3 = Bt + (size_t)(colbase + 96 ) * 256 + kh * 16;
        #pragma unroll
        for (int kk = 0; kk < 8; ++kk) {
            bf0[kk] = *reinterpret_cast<const v4i*>(bp0 + kk * 32);
            bf1[kk] = *reinterpret_cast<const v4i*>(bp1 + kk * 32);
            bf2[kk] = *reinterpret_cast<const v4i*>(bp2 + kk * 32);
            bf3[kk] = *reinterpret_cast<const v4i*>(bp3 + kk * 32);
        }
    }
    const u32 base0 = ((u32)tesum[colbase      ] << 16);
    const u32 base1 = ((u32)tesum[colbase + 32 ] << 16);
    const u32 base2 = ((u32)tesum[colbase + 64 ] << 16);
    const u32 base3 = ((u32)tesum[colbase + 96 ] << 16);

    u32 q00 = 0x7FFFFFFFu, q01 = 0x7FFFFFFFu, q02 = 0x7FFFFFFFu;
    u32 q10 = 0x7FFFFFFFu, q11 = 0x7FFFFFFFu, q12 = 0x7FFFFFFFu;
    u32 q20 = 0x7FFFFFFFu, q21 = 0x7FFFFFFFu, q22 = 0x7FFFFFFFu;
    u32 q30 = 0x7FFFFFFFu, q31 = 0x7FFFFFFFu, q32 = 0x7FFFFFFFu;

    const char* ap = A + ((size_t)c * CHROWS + a) * 256 + kh * 16;

    #pragma unroll 1
    for (int t = 0; t < TILES; ++t) {
        v16i A0 = {0,0,0,0,0,0,0,0,0,0,0,0,0,0,0,0};
        v16i A1 = {0,0,0,0,0,0,0,0,0,0,0,0,0,0,0,0};
        v16i A2 = {0,0,0,0,0,0,0,0,0,0,0,0,0,0,0,0};
        v16i A3 = {0,0,0,0,0,0,0,0,0,0,0,0,0,0,0,0};
        const char* apt = ap + (size_t)t * (32 * 256);
        #pragma unroll
        for (int kk = 0; kk < 8; ++kk) {
            v4i af = *reinterpret_cast<const v4i*>(apt + kk * 32);
            A0 = __builtin_amdgcn_mfma_i32_32x32x32_i8(af, bf0[kk], A0, 0, 0, 0);
            A1 = __builtin_amdgcn_mfma_i32_32x32x32_i8(af, bf1[kk], A1, 0, 0, 0);
            A2 = __builtin_amdgcn_mfma_i32_32x32x32_i8(af, bf2[kk], A2, 0, 0, 0);
            A3 = __builtin_amdgcn_mfma_i32_32x32x32_i8(af, bf3[kk], A3, 0, 0, 0);
        }
        const int tbase = c * CHROWS + t * 32;
        const u32 kb = (u32)(tbase + 4 * kh);
        if (tbase + 32 <= NUM_TRAIN) {               // uniform fast path
            #pragma unroll
            for (int g = 0; g < 16; ++g) {
                const int row = (g & 3) + 8 * (g >> 2);
                insert3(q00, q01, q02, ((u32)A0[g] << 16) + base0 + kb + (u32)row);
                insert3(q10, q11, q12, ((u32)A1[g] << 16) + base1 + kb + (u32)row);
                insert3(q20, q21, q22, ((u32)A2[g] << 16) + base2 + kb + (u32)row);
                insert3(q30, q31, q32, ((u32)A3[g] << 16) + base3 + kb + (u32)row);
            }
        } else {                                     // boundary/pad tiles only
            #pragma unroll
            for (int g = 0; g < 16; ++g) {
                const int row = (g & 3) + 8 * (g >> 2);
                const int idx = tbase + 4 * kh + row;
                const bool ok = (idx < NUM_TRAIN);
                insert3(q00, q01, q02, ok ? (((u32)A0[g] << 16) + base0 + kb + (u32)row) : 0xFFFFFFFFu);
                insert3(q10, q11, q12, ok ? (((u32)A1[g] << 16) + base1 + kb + (u32)row) : 0xFFFFFFFFu);
                insert3(q20, q21, q22, ok ? (((u32)A2[g] << 16) + base2 + kb + (u32)row) : 0xFFFFFFFFu);
                insert3(q30, q31, q32, ok ? (((u32)A3[g] << 16) + base3 + kb + (u32)row) : 0xFFFFFFFFu);
            }
        }
    }

    // lanes l / l+32 hold complementary row-halves of the same test col
    u32 o0, o1, o2;
    o0 = __shfl_xor(q00, 32); o1 = __shfl_xor(q01, 32); o2 = __shfl_xor(q02, 32);
    merge3(q00, q01, q02, o0, o1, o2);
    o0 = __shfl_xor(q10, 32); o1 = __shfl_xor(q11, 32); o2 = __shfl_xor(q12, 32);
    merge3(q10, q11, q12, o0, o1, o2);
    o0 = __shfl_xor(q20, 32); o1 = __shfl_xor(q21, 32); o2 = __shfl_xor(q22, 32);
    merge3(q20, q21, q22, o0, o1, o2);
    o0 = __shfl_xor(q30, 32); o1 = __shfl_xor(q31, 32); o2 = __shfl_xor(q32, 32);
    merge3(q30, q31, q32, o0, o1, o2);
    if (kh == 0) {
        u32* d0 = partial + ((size_t)(colbase      ) * NCH + c) * 3;
        d0[0] = q00; d0[1] = q01; d0[2] = q02;
        u32* d1 = partial + ((size_t)(colbase + 32 ) * NCH + c) * 3;
        d1[0] = q10; d1[1] = q11; d1[2] = q12;
        u32* d2 = partial + ((size_t)(colbase + 64 ) * NCH + c) * 3;
        d2[0] = q20; d2[1] = q21; d2[2] = q22;
        u32* d3 = partial + ((size_t)(colbase + 96 ) * NCH + c) * 3;
        d3[0] = q30; d3[1] = q31; d3[2] = q32;
    }
}

// Vote kernel: merge NCH partial triples per sample; majority vote with
// argmax-first-max tie semantics (validated R2/R5/R6/R9/R10/R12/R13).
template<int NCH>
__global__ __launch_bounds__(256) void vote_knn(const u32* __restrict__ partial,
                                                int* __restrict__ out) {
    int t = blockIdx.x * 256 + threadIdx.x;
    if (t >= NUM_TEST) return;
    const u32* p = partial + (size_t)t * NCH * 3;
    u32 a0 = p[0], a1 = p[1], a2 = p[2];
    for (int c = 1; c < NCH; ++c)
        merge3(a0, a1, a2, p[c * 3 + 0], p[c * 3 + 1], p[c * 3 + 2]);
    const int l0 = (int)(a0 & 0xFFFFu) / CLASS_SIZE;
    const int l1 = (int)(a1 & 0xFFFFu) / CLASS_SIZE;
    const int l2 = (int)(a2 & 0xFFFFu) / CLASS_SIZE;
    int winner;
    if (l0 == l1 || l0 == l2)      winner = l0;
    else if (l1 == l2)             winner = l1;
    else winner = min(l0, min(l1, l2));
    out[t] = winner;
}

// ======================= validated R5 fallback path ========================
#define TT          8
#define NCHUNK      4
#define CHUNK_ROWS  (NUM_TRAIN / NCHUNK)

__global__ void pack_kernel(const int* __restrict__ train,
                            const int* __restrict__ test,
                            u64* __restrict__ packed) {
    int wave = (blockIdx.x * blockDim.x + threadIdx.x) >> 6;
    int lane = threadIdx.x & 63;
    const int* src = (wave < NUM_TRAIN)
                       ? (train + (size_t)wave * 256)
                       : (test + (size_t)(wave - NUM_TRAIN) * 256);
    int4 v = *reinterpret_cast<const int4*>(src + lane * 4);
    u64 b0 = __ballot(v.x & 1);
    u64 b1 = __ballot(v.y & 1);
    u64 b2 = __ballot(v.z & 1);
    u64 b3 = __ballot(v.w & 1);
    if (lane == 0) {
        u64* dst = packed + (size_t)wave * 4;
        dst[0] = b0; dst[1] = b1; dst[2] = b2; dst[3] = b3;
    }
}

__global__ __launch_bounds__(256) void knn_kernel(const u32* __restrict__ packed,
                                                  u32* __restrict__ partial) {
    const int g    = blockIdx.x >> 2;
    const int c    = blockIdx.x & 3;
    const int tid  = threadIdx.x;
    const int base = g * TT;
    const uint4* rows  = (const uint4*)packed;
    const u32*  testp  = packed + (size_t)NUM_TRAIN * 8;

    u32 te[TT][8];
    #pragma unroll
    for (int s = 0; s < TT; ++s) {
        const u32* p = testp + (size_t)(base + s) * 8;
        #pragma unroll
        for (int j = 0; j < 8; ++j) te[s][j] = p[j];
    }
    u32 k0[TT], k1[TT], k2[TT];
    #pragma unroll
    for (int s = 0; s < TT; ++s) { k0[s] = k1[s] = k2[s] = 0x7FFFFFFFu; }

    const int start = c * CHUNK_ROWS;
    const int end   = start + CHUNK_ROWS;
    for (int r = start + tid; r < end; r += 256) {
        uint4 a0 = rows[(size_t)r * 2];
        uint4 a1 = rows[(size_t)r * 2 + 1];
        #pragma unroll
        for (int s = 0; s < TT; ++s) {
            int d = __popc(a0.x ^ te[s][0]);
            d += __popc(a0.y ^ te[s][1]);
            d += __popc(a0.z ^ te[s][2]);
            d += __popc(a0.w ^ te[s][3]);
            d += __popc(a1.x ^ te[s][4]);
            d += __popc(a1.y ^ te[s][5]);
            d += __popc(a1.z ^ te[s][6]);
            d += __popc(a1.w ^ te[s][7]);
            u32 key = ((u32)d << 16) | (u32)r;
            insert3(k0[s], k1[s], k2[s], key);
        }
    }
    #pragma unroll
    for (int s = 0; s < TT; ++s) {
        for (int off = 1; off < 64; off <<= 1) {
            u32 o0 = __shfl_xor(k0[s], off);
            u32 o1 = __shfl_xor(k1[s], off);
            u32 o2 = __shfl_xor(k2[s], off);
            merge3(k0[s], k1[s], k2[s], o0, o1, o2);
        }
    }
    __shared__ u32 red[4][TT][3];
    const int wave = tid >> 6, lane = tid & 63;
    if (lane == 0) {
        #pragma unroll
        for (int s = 0; s < TT; ++s) {
            red[wave][s][0] = k0[s];
            red[wave][s][1] = k1[s];
            red[wave][s][2] = k2[s];
        }
    }
    __syncthreads();
    if (tid < TT) {
        const int s = tid;
        u32 a0 = red[0][s][0], a1 = red[0][s][1], a2 = red[0][s][2];
        #pragma unroll
        for (int w = 1; w < 4; ++w)
            merge3(a0, a1, a2, red[w][s][0], red[w][s][1], red[w][s][2]);
        u32* dst = partial + ((size_t)(base + s) * NCHUNK + c) * 3;
        dst[0] = a0; dst[1] = a1; dst[2] = a2;
    }
}

__global__ __launch_bounds__(256) void merge_kernel(const u32* __restrict__ partial,
                                                    int* __restrict__ out) {
    int t = blockIdx.x * blockDim.x + threadIdx.x;
    if (t >= NUM_TEST) return;
    const u32* p = partial + (size_t)t * NCHUNK * 3;
    u32 a0 = p[0], a1 = p[1], a2 = p[2];
    #pragma unroll
    for (int c = 1; c < NCHUNK; ++c)
        merge3(a0, a1, a2, p[c * 3 + 0], p[c * 3 + 1], p[c * 3 + 2]);
    const int l0 = (int)(a0 & 0xFFFFu) / CLASS_SIZE;
    const int l1 = (int)(a1 & 0xFFFFu) / CLASS_SIZE;
    const int l2 = (int)(a2 & 0xFFFFu) / CLASS_SIZE;
    int winner;
    if (l0 == l1 || l0 == l2)      winner = l0;
    else if (l1 == l2)             winner = l1;
    else winner = min(l0, min(l1, l2));
    out[t] = winner;
}
// ===========================================================================

extern "C" void kernel_launch(void* const* d_in, const int* in_sizes, int n_in,
                              void* d_out, int out_size, void* d_ws, size_t ws_size,
                              hipStream_t stream) {
    const int* train = (const int*)d_in[0];
    const int* test  = (const int*)d_in[1];
    int* out = (int*)d_out;

    if (ws_size >= WS_NEED(56)) {
        char* train_i8 = (char*)d_ws;
        char* test_i8  = (char*)d_ws + OFF_TEST;
        int*  tesum    = (int*)((char*)d_ws + OFF_TESUM);
        u32*  partial  = (u32*)((char*)d_ws + OFF_PART);

        pack_train_bits<<<TRAIN_PAD / 4, 256, 0, stream>>>(train, train_i8);
        pack_test_pm1<<<NUM_TEST / 4, 256, 0, stream>>>(test, test_i8, tesum);
        if (ws_size >= WS_NEED(112)) {
            mfma_knn<112><<<8 * 112, 256, 0, stream>>>(train_i8, test_i8, tesum, partial);
            vote_knn<112><<<NUM_TEST / 256, 256, 0, stream>>>(partial, out);
        } else {
            mfma_knn<56><<<8 * 56, 256, 0, stream>>>(train_i8, test_i8, tesum, partial);
            vote_knn<56><<<NUM_TEST / 256, 256, 0, stream>>>(partial, out);
        }
    } else {
        // validated R5 path (1.93 MB ws)
        u64* packed = (u64*)d_ws;
        u32* partial = (u32*)((char*)d_ws + (size_t)(NUM_TRAIN + NUM_TEST) * 4 * sizeof(u64));
        const int total_rows = NUM_TRAIN + NUM_TEST;
        pack_kernel<<<total_rows / 4, 256, 0, stream>>>(train, test, packed);
        knn_kernel<<<(NUM_TEST / TT) * NCHUNK, 256, 0, stream>>>((const u32*)packed, partial);
        merge_kernel<<<(NUM_TEST + 255) / 256, 256, 0, stream>>>(partial, out);
    }
}

// Round 15
// 87.299 us; speedup vs baseline: 1.3655x; 1.3655x over previous
//
#include <hip/hip_runtime.h>
#include <stdint.h>

typedef unsigned long long u64;
typedef unsigned int u32;
typedef int v4i  __attribute__((ext_vector_type(4)));
typedef int v16i __attribute__((ext_vector_type(16)));

#define NUM_TRAIN   50000
#define NUM_TEST    4096
#define CLASS_SIZE  5000
#define TRAIN_PAD   50176              // 1568 tiles of 32 rows
#define TOT_TILES   1568

// ws layout: train_i8 | test_i8 | te_sum | partial
#define SZ_TRAIN   ((size_t)TRAIN_PAD * 256)          // 12,845,056
#define SZ_TEST    ((size_t)NUM_TEST * 256)           //  1,048,576
#define SZ_TESUM   ((size_t)NUM_TEST * 4)             //     16,384
#define OFF_TEST   (SZ_TRAIN)
#define OFF_TESUM  (OFF_TEST + SZ_TEST)
#define OFF_PART   (OFF_TESUM + SZ_TESUM)             // 13,910,016
#define WS_NEED(NCH) (OFF_PART + (size_t)NUM_TEST * (NCH) * 3 * 4)

// ---------------------------------------------------------------------------
// Top-3 primitives. key = (dist<<16)+idx encodes the reference
// (dist asc, then smaller index) tie-break exactly (validated R2..R13).
// R15: insert3 via v_med3_u32 (3 VALU instead of 5). Derivation for sorted
// (k0<=k1<=k2), inserting x:  k0'=min(k0,x); k1'=med3(k0,k1,x);
// k2'=med3(k1,k2,x) — verified over all four insertion positions.
// Both med3s read OLD k-values; k0 is updated last.
// ---------------------------------------------------------------------------
__device__ __forceinline__ void insert3(u32& k0, u32& k1, u32& k2, u32 key) {
    u32 m1, m2;
    asm("v_med3_u32 %0, %1, %2, %3" : "=v"(m1) : "v"(k0), "v"(k1), "v"(key));
    asm("v_med3_u32 %0, %1, %2, %3" : "=v"(m2) : "v"(k1), "v"(k2), "v"(key));
    k0 = min(k0, key);
    k1 = m1; k2 = m2;
}
__device__ __forceinline__ void merge3(u32& a0, u32& a1, u32& a2,
                                       u32 b0, u32 b1, u32 b2) {
    u32 hi0 = max(a0, b0);
    u32 lo1 = min(a1, b1);
    u32 c0  = min(a0, b0);
    u32 c1  = min(hi0, lo1);
    u32 c2  = min(max(lo1, hi0), min(a2, b2));
    a0 = c0; a1 = c1; a2 = c2;
}
__device__ __forceinline__ int wave_sum(int s) {
    #pragma unroll
    for (int off = 1; off < 64; off <<= 1) s += __shfl_xor(s, off);
    return s;
}

// ---------------------------------------------------------------------------
// pack_all (R15: fused): global wave id r < TRAIN_PAD -> train row (byte=bit,
// pad rows zero); else test row (byte = 1-2*bit, +tesum). One launch.
// ---------------------------------------------------------------------------
__global__ __launch_bounds__(256) void pack_all(const int* __restrict__ train,
                                                const int* __restrict__ test,
                                                char* __restrict__ dstA,
                                                char* __restrict__ dstB,
                                                int* __restrict__ tesum) {
    int r    = (blockIdx.x * 256 + threadIdx.x) >> 6;
    int lane = threadIdx.x & 63;
    if (r < TRAIN_PAD) {
        int4 v = make_int4(0, 0, 0, 0);
        if (r < NUM_TRAIN)
            v = *reinterpret_cast<const int4*>(train + (size_t)r * 256 + lane * 4);
        u32 w = (u32)(v.x & 1) | ((u32)(v.y & 1) << 8)
              | ((u32)(v.z & 1) << 16) | ((u32)(v.w & 1) << 24);
        *reinterpret_cast<u32*>(dstA + (size_t)r * 256 + lane * 4) = w;
    } else {
        int rt = r - TRAIN_PAD;
        int4 v = *reinterpret_cast<const int4*>(test + (size_t)rt * 256 + lane * 4);
        u32 w = (u32)((1 - 2 * v.x) & 0xFF) | ((u32)((1 - 2 * v.y) & 0xFF) << 8)
              | ((u32)((1 - 2 * v.z) & 0xFF) << 16) | ((u32)((1 - 2 * v.w) & 0xFF) << 24);
        *reinterpret_cast<u32*>(dstB + (size_t)rt * 256 + lane * 4) = w;
        int total = wave_sum(v.x + v.y + v.z + v.w);
        if (lane == 0) tesum[rt] = total;
    }
}

// ---------------------------------------------------------------------------
// mfma_knn (R15): R12 structure + TWO tiles per barrier phase.
//   - R10-validated conflict-free LDS layout per 8KB sub-buffer:
//     fragment (kk,kh,row) at kk*1024 + kh*512 + ((row^kk)&31)*16.
//   - lds[2 bufs][2 tiles x 8192]. Phase p: compute tiles 2p,2p+1 from buf
//     (p&1), stage tiles 2p+2,2p+3 into buf (p&1)^1, ONE barrier per phase.
//     Loads issued at phase start, ds_writes at phase end (T14 split).
//   - Hazards: writes to buf W in phase p vs reads of W in p-1/p+1 separated
//     by exactly one barrier. 14 phases (NCH=56), even.
// acc = tr_sum - 2*inner; dist = acc + te_sum folded into the key base.
// Guarded epilogue nulls pad rows (idx >= 50000) on boundary tiles only.
// ---------------------------------------------------------------------------
template<int NCH>
__global__ __launch_bounds__(256) void mfma_knn(const char* __restrict__ A,
                                                const char* __restrict__ Bt,
                                                const int* __restrict__ tesum,
                                                u32* __restrict__ partial) {
    constexpr int TILES  = TOT_TILES / NCH;    // 28 (NCH=56)
    constexpr int PHASES = TILES / 2;          // 14
    constexpr int CHROWS = TRAIN_PAD / NCH;    // 896
    static_assert((TILES & 3) == 0, "need TILES % 4 == 0 for 2-phase x 2-tile loop");
    const int cg   = blockIdx.x / NCH;
    const int c    = blockIdx.x % NCH;
    const int tid  = threadIdx.x;
    const int wid  = tid >> 6;
    const int lane = tid & 63;
    const int a    = lane & 31;                // A-row within tile / B-col lane
    const int kh   = lane >> 5;                // K-half

    // Two B-fragment sets: this wave's 64 test cols, 8 K-steps, in registers.
    const int col0 = cg * 256 + wid * 64 + a;
    const int col1 = col0 + 32;
    v4i bf0[8], bf1[8];
    {
        const char* bp0 = Bt + (size_t)col0 * 256 + kh * 16;
        const char* bp1 = Bt + (size_t)col1 * 256 + kh * 16;
        #pragma unroll
        for (int kk = 0; kk < 8; ++kk) {
            bf0[kk] = *reinterpret_cast<const v4i*>(bp0 + kk * 32);
            bf1[kk] = *reinterpret_cast<const v4i*>(bp1 + kk * 32);
        }
    }
    const u32 base0 = ((u32)tesum[col0] << 16);   // te_sum folded into key
    const u32 base1 = ((u32)tesum[col1] << 16);

    __shared__ char lds[2][16384];             // [buf][2 tiles x 8192]
    char* rd[8];                               // buf0/sub0 read addrs per kk
    #pragma unroll
    for (int kk = 0; kk < 8; ++kk)
        rd[kk] = &lds[0][kk * 1024 + kh * 512 + ((a ^ kk) & 31) * 16];

    // staging: thread t covers row grow, bytes [gc*32, +32) (coalesced t*32)
    const int grow = tid >> 3, gc = tid & 7;
    const char* gsrc0 = A + (size_t)c * CHROWS * 256 + grow * 256 + gc * 32;
    char* w0 = &lds[0][gc * 1024 +       ((grow ^ gc) & 31) * 16];   // kh=0
    char* w1 = &lds[0][gc * 1024 + 512 + ((grow ^ gc) & 31) * 16];   // kh=1

    u32 p00 = 0x7FFFFFFFu, p01 = 0x7FFFFFFFu, p02 = 0x7FFFFFFFu;
    u32 p10 = 0x7FFFFFFFu, p11 = 0x7FFFFFFFu, p12 = 0x7FFFFFFFu;

    // prologue: stage tiles 0,1 into buf 0 (subs 0,1)
    {
        uint4 s0 = *reinterpret_cast<const uint4*>(gsrc0);
        uint4 s1 = *reinterpret_cast<const uint4*>(gsrc0 + 16);
        uint4 s2 = *reinterpret_cast<const uint4*>(gsrc0 + 8192);
        uint4 s3 = *reinterpret_cast<const uint4*>(gsrc0 + 8192 + 16);
        *reinterpret_cast<uint4*>(w0)        = s0;
        *reinterpret_cast<uint4*>(w1)        = s1;
        *reinterpret_cast<uint4*>(w0 + 8192) = s2;
        *reinterpret_cast<uint4*>(w1 + 8192) = s3;
    }
    __syncthreads();

// Compute one tile TT from buf RB sub SUB and insert into tops.
#define TILE_COMPUTE(TT, RB, SUB)                                             \
    {                                                                         \
        const int tt = (TT);                                                  \
        v16i acc0 = {0,0,0,0,0,0,0,0,0,0,0,0,0,0,0,0};                        \
        v16i acc1 = {0,0,0,0,0,0,0,0,0,0,0,0,0,0,0,0};                        \
        _Pragma("unroll")                                                     \
        for (int kk = 0; kk < 8; ++kk) {                                      \
            v4i af = *reinterpret_cast<const v4i*>(rd[kk] + (RB) * 16384 + (SUB) * 8192); \
            acc0 = __builtin_amdgcn_mfma_i32_32x32x32_i8(af, bf0[kk], acc0, 0, 0, 0); \
            acc1 = __builtin_amdgcn_mfma_i32_32x32x32_i8(af, bf1[kk], acc1, 0, 0, 0); \
        }                                                                     \
        const int tbase = c * CHROWS + tt * 32;                               \
        const u32 kb0 = base0 + (u32)(tbase + 4 * kh);                        \
        const u32 kb1 = base1 + (u32)(tbase + 4 * kh);                        \
        if (tbase + 32 <= NUM_TRAIN) {                                        \
            _Pragma("unroll")                                                 \
            for (int g = 0; g < 16; ++g) {                                    \
                const int row = (g & 3) + 8 * (g >> 2);                       \
                insert3(p00, p01, p02, ((u32)acc0[g] << 16) + kb0 + (u32)row);\
                insert3(p10, p11, p12, ((u32)acc1[g] << 16) + kb1 + (u32)row);\
            }                                                                 \
        } else {                                                              \
            _Pragma("unroll")                                                 \
            for (int g = 0; g < 16; ++g) {                                    \
                const int row = (g & 3) + 8 * (g >> 2);                       \
                const int idx = tbase + 4 * kh + row;                         \
                u32 key0 = (idx < NUM_TRAIN)                                  \
                    ? (((u32)acc0[g] << 16) + kb0 + (u32)row) : 0xFFFFFFFFu;  \
                u32 key1 = (idx < NUM_TRAIN)                                  \
                    ? (((u32)acc1[g] << 16) + kb1 + (u32)row) : 0xFFFFFFFFu;  \
                insert3(p00, p01, p02, key0);                                 \
                insert3(p10, p11, p12, key1);                                 \
            }                                                                 \
        }                                                                     \
    }

// Phase P: compute tiles 2P,2P+1 from buf RB; stage tiles 2P+2,2P+3 into WB.
// Loads issued first (T14), ds_writes last, ONE barrier.
#define PHASE(P, RB, WB)                                                      \
    {                                                                         \
        const int pp = (P);                                                   \
        uint4 s0, s1, s2, s3;                                                 \
        const bool pf = (pp + 1 < PHASES);                                    \
        if (pf) {                                                             \
            const char* g0 = gsrc0 + (size_t)(2 * pp + 2) * 8192;             \
            s0 = *reinterpret_cast<const uint4*>(g0);                         \
            s1 = *reinterpret_cast<const uint4*>(g0 + 16);                    \
            s2 = *reinterpret_cast<const uint4*>(g0 + 8192);                  \
            s3 = *reinterpret_cast<const uint4*>(g0 + 8192 + 16);             \
        }                                                                     \
        TILE_COMPUTE(2 * pp,     RB, 0)                                       \
        TILE_COMPUTE(2 * pp + 1, RB, 1)                                       \
        if (pf) {                                                             \
            *reinterpret_cast<uint4*>(w0 + (WB) * 16384)        = s0;         \
            *reinterpret_cast<uint4*>(w1 + (WB) * 16384)        = s1;         \
            *reinterpret_cast<uint4*>(w0 + (WB) * 16384 + 8192) = s2;         \
            *reinterpret_cast<uint4*>(w1 + (WB) * 16384 + 8192) = s3;         \
        }                                                                     \
        __syncthreads();                                                      \
    }

    #pragma unroll 1
    for (int p = 0; p < PHASES; p += 2) {
        PHASE(p,     0, 1)
        PHASE(p + 1, 1, 0)
    }
#undef PHASE
#undef TILE_COMPUTE

    // lanes l / l+32 hold complementary row-halves of the same test col
    u32 o0, o1, o2;
    o0 = __shfl_xor(p00, 32); o1 = __shfl_xor(p01, 32); o2 = __shfl_xor(p02, 32);
    merge3(p00, p01, p02, o0, o1, o2);
    o0 = __shfl_xor(p10, 32); o1 = __shfl_xor(p11, 32); o2 = __shfl_xor(p12, 32);
    merge3(p10, p11, p12, o0, o1, o2);
    if (kh == 0) {
        u32* d0 = partial + ((size_t)col0 * NCH + c) * 3;
        d0[0] = p00; d0[1] = p01; d0[2] = p02;
        u32* d1 = partial + ((size_t)col1 * NCH + c) * 3;
        d1[0] = p10; d1[1] = p11; d1[2] = p12;
    }
}

// Vote kernel: merge NCH partial triples per sample; majority vote with
// argmax-first-max tie semantics (validated R2..R13).
template<int NCH>
__global__ __launch_bounds__(256) void vote_knn(const u32* __restrict__ partial,
                                                int* __restrict__ out) {
    int t = blockIdx.x * 256 + threadIdx.x;
    if (t >= NUM_TEST) return;
    const u32* p = partial + (size_t)t * NCH * 3;
    u32 a0 = p[0], a1 = p[1], a2 = p[2];
    for (int c = 1; c < NCH; ++c)
        merge3(a0, a1, a2, p[c * 3 + 0], p[c * 3 + 1], p[c * 3 + 2]);
    const int l0 = (int)(a0 & 0xFFFFu) / CLASS_SIZE;
    const int l1 = (int)(a1 & 0xFFFFu) / CLASS_SIZE;
    const int l2 = (int)(a2 & 0xFFFFu) / CLASS_SIZE;
    int winner;
    if (l0 == l1 || l0 == l2)      winner = l0;
    else if (l1 == l2)             winner = l1;
    else winner = min(l0, min(l1, l2));
    out[t] = winner;
}

// ======================= validated R5 fallback path ========================
#define TT          8
#define NCHUNK      4
#define CHUNK_ROWS  (NUM_TRAIN / NCHUNK)

__device__ __forceinline__ void insert3_minmax(u32& k0, u32& k1, u32& k2, u32 key) {
    u32 m0 = min(k0, key);
    u32 m1 = min(k1, max(k0, key));
    u32 m2 = min(k2, max(k1, key));
    k0 = m0; k1 = m1; k2 = m2;
}

__global__ void pack_kernel(const int* __restrict__ train,
                            const int* __restrict__ test,
                            u64* __restrict__ packed) {
    int wave = (blockIdx.x * blockDim.x + threadIdx.x) >> 6;
    int lane = threadIdx.x & 63;
    const int* src = (wave < NUM_TRAIN)
                       ? (train + (size_t)wave * 256)
                       : (test + (size_t)(wave - NUM_TRAIN) * 256);
    int4 v = *reinterpret_cast<const int4*>(src + lane * 4);
    u64 b0 = __ballot(v.x & 1);
    u64 b1 = __ballot(v.y & 1);
    u64 b2 = __ballot(v.z & 1);
    u64 b3 = __ballot(v.w & 1);
    if (lane == 0) {
        u64* dst = packed + (size_t)wave * 4;
        dst[0] = b0; dst[1] = b1; dst[2] = b2; dst[3] = b3;
    }
}

__global__ __launch_bounds__(256) void knn_kernel(const u32* __restrict__ packed,
                                                  u32* __restrict__ partial) {
    const int g    = blockIdx.x >> 2;
    const int c    = blockIdx.x & 3;
    const int tid  = threadIdx.x;
    const int base = g * TT;
    const uint4* rows  = (const uint4*)packed;
    const u32*  testp  = packed + (size_t)NUM_TRAIN * 8;

    u32 te[TT][8];
    #pragma unroll
    for (int s = 0; s < TT; ++s) {
        const u32* p = testp + (size_t)(base + s) * 8;
        #pragma unroll
        for (int j = 0; j < 8; ++j) te[s][j] = p[j];
    }
    u32 k0[TT], k1[TT], k2[TT];
    #pragma unroll
    for (int s = 0; s < TT; ++s) { k0[s] = k1[s] = k2[s] = 0x7FFFFFFFu; }

    const int start = c * CHUNK_ROWS;
    const int end   = start + CHUNK_ROWS;
    for (int r = start + tid; r < end; r += 256) {
        uint4 a0 = rows[(size_t)r * 2];
        uint4 a1 = rows[(size_t)r * 2 + 1];
        #pragma unroll
        for (int s = 0; s < TT; ++s) {
            int d = __popc(a0.x ^ te[s][0]);
            d += __popc(a0.y ^ te[s][1]);
            d += __popc(a0.z ^ te[s][2]);
            d += __popc(a0.w ^ te[s][3]);
            d += __popc(a1.x ^ te[s][4]);
            d += __popc(a1.y ^ te[s][5]);
            d += __popc(a1.z ^ te[s][6]);
            d += __popc(a1.w ^ te[s][7]);
            u32 key = ((u32)d << 16) | (u32)r;
            insert3_minmax(k0[s], k1[s], k2[s], key);
        }
    }
    #pragma unroll
    for (int s = 0; s < TT; ++s) {
        for (int off = 1; off < 64; off <<= 1) {
            u32 o0 = __shfl_xor(k0[s], off);
            u32 o1 = __shfl_xor(k1[s], off);
            u32 o2 = __shfl_xor(k2[s], off);
            merge3(k0[s], k1[s], k2[s], o0, o1, o2);
        }
    }
    __shared__ u32 red[4][TT][3];
    const int wave = tid >> 6, lane = tid & 63;
    if (lane == 0) {
        #pragma unroll
        for (int s = 0; s < TT; ++s) {
            red[wave][s][0] = k0[s];
            red[wave][s][1] = k1[s];
            red[wave][s][2] = k2[s];
        }
    }
    __syncthreads();
    if (tid < TT) {
        const int s = tid;
        u32 a0 = red[0][s][0], a1 = red[0][s][1], a2 = red[0][s][2];
        #pragma unroll
        for (int w = 1; w < 4; ++w)
            merge3(a0, a1, a2, red[w][s][0], red[w][s][1], red[w][s][2]);
        u32* dst = partial + ((size_t)(base + s) * NCHUNK + c) * 3;
        dst[0] = a0; dst[1] = a1; dst[2] = a2;
    }
}

__global__ __launch_bounds__(256) void merge_kernel(const u32* __restrict__ partial,
                                                    int* __restrict__ out) {
    int t = blockIdx.x * blockDim.x + threadIdx.x;
    if (t >= NUM_TEST) return;
    const u32* p = partial + (size_t)t * NCHUNK * 3;
    u32 a0 = p[0], a1 = p[1], a2 = p[2];
    #pragma unroll
    for (int c = 1; c < NCHUNK; ++c)
        merge3(a0, a1, a2, p[c * 3 + 0], p[c * 3 + 1], p[c * 3 + 2]);
    const int l0 = (int)(a0 & 0xFFFFu) / CLASS_SIZE;
    const int l1 = (int)(a1 & 0xFFFFu) / CLASS_SIZE;
    const int l2 = (int)(a2 & 0xFFFFu) / CLASS_SIZE;
    int winner;
    if (l0 == l1 || l0 == l2)      winner = l0;
    else if (l1 == l2)             winner = l1;
    else winner = min(l0, min(l1, l2));
    out[t] = winner;
}
// ===========================================================================

extern "C" void kernel_launch(void* const* d_in, const int* in_sizes, int n_in,
                              void* d_out, int out_size, void* d_ws, size_t ws_size,
                              hipStream_t stream) {
    const int* train = (const int*)d_in[0];
    const int* test  = (const int*)d_in[1];
    int* out = (int*)d_out;

    if (ws_size >= WS_NEED(56)) {
        char* train_i8 = (char*)d_ws;
        char* test_i8  = (char*)d_ws + OFF_TEST;
        int*  tesum    = (int*)((char*)d_ws + OFF_TESUM);
        u32*  partial  = (u32*)((char*)d_ws + OFF_PART);

        pack_all<<<(TRAIN_PAD + NUM_TEST) / 4, 256, 0, stream>>>(train, test,
                                                                 train_i8, test_i8, tesum);
        mfma_knn<56><<<16 * 56, 256, 0, stream>>>(train_i8, test_i8, tesum, partial);
        vote_knn<56><<<NUM_TEST / 256, 256, 0, stream>>>(partial, out);
    } else {
        // validated R5 path (1.93 MB ws)
        u64* packed = (u64*)d_ws;
        u32* partial = (u32*)((char*)d_ws + (size_t)(NUM_TRAIN + NUM_TEST) * 4 * sizeof(u64));
        const int total_rows = NUM_TRAIN + NUM_TEST;
        pack_kernel<<<total_rows / 4, 256, 0, stream>>>(train, test, packed);
        knn_kernel<<<(NUM_TEST / TT) * NCHUNK, 256, 0, stream>>>((const u32*)packed, partial);
        merge_kernel<<<(NUM_TEST + 255) / 256, 256, 0, stream>>>(partial, out);
    }
}